// Round 12
// baseline (61.363 us; speedup 1.0000x reference)
//
#include <hip/hip_runtime.h>

#define IMH 512
#define IMW 512
#define BATCH 8
#define NTOK 20480
#define NC 4096
#define NF 16384
#define ED 128

// ---------------- Kernel 1: coarse embed (blocks 0-1023) + edge map (1024-1535)
__global__ __launch_bounds__(256) void k1_edge_coarse(const float* __restrict__ x,
                                                      const float* __restrict__ wc,
                                                      const float* __restrict__ bc,
                                                      const float* __restrict__ temb,
                                                      float* __restrict__ out,
                                                      double* __restrict__ edges,
                                                      double* __restrict__ tsum) {
    __shared__ float esm[66][68];
    __shared__ double dred[4];
    int blk = blockIdx.x;
    int t = threadIdx.x;
    int lane = t & 63, wid = t >> 6;
    if (blk < 1024) {
        // ---- coarse role: 32 patches/block, wave-uniform scalar loads, no LDS
        int b = blk >> 7;
        int pblk = (blk & 127) * 32;
        int wv = __builtin_amdgcn_readfirstlane(t >> 6);  // wave id 0..3
        int h = wv & 1;
        int p0 = pblk + (wv >> 1) * 16;
        int d = h * 64 + lane;
        float wcol[64];
        #pragma unroll
        for (int k = 0; k < 64; ++k) wcol[k] = wc[k * ED + d];
        float base = bc[d] + temb[d];
        const float* img = x + ((size_t)b * IMH + (p0 >> 6) * 8) * IMW + (p0 & 63) * 8;
        float* dst = out + ((size_t)b * NTOK + p0) * ED + d;
        #pragma unroll
        for (int p = 0; p < 16; ++p) {
            const float* pimg = img + p * 8;    // wave-uniform -> scalar loads
            float acc = base;
            #pragma unroll
            for (int r = 0; r < 8; ++r) {
                const float* rp = pimg + r * IMW;
                acc += rp[0] * wcol[r * 8 + 0] + rp[1] * wcol[r * 8 + 1]
                     + rp[2] * wcol[r * 8 + 2] + rp[3] * wcol[r * 8 + 3]
                     + rp[4] * wcol[r * 8 + 4] + rp[5] * wcol[r * 8 + 5]
                     + rp[6] * wcol[r * 8 + 6] + rp[7] * wcol[r * 8 + 7];
            }
            dst[(size_t)p * ED] = acc;
        }
    } else {
        // ---- edge role: one 64x64 tile -> 16x16 fp64 cells + fp64 tile sum
        int blk2 = blk - 1024;
        int b = blk2 >> 6;
        int tile = blk2 & 63;
        int ty0 = (tile >> 3) * 64;
        int tx0 = (tile & 7) * 64;
        const float* img = x + (size_t)b * (IMH * IMW);
        for (int idx = t; idx < 66 * 66; idx += 256) {
            int r = idx / 66, c = idx - r * 66;
            int gy = ty0 - 1 + r, gx = tx0 - 1 + c;
            float v = 0.f;
            if (gy >= 0 && gy < IMH && gx >= 0 && gx < IMW) v = img[gy * IMW + gx];
            esm[r][c] = v;
        }
        __syncthreads();
        int cy = t >> 4, cx = t & 15;
        double acc = 0.0;
        #pragma unroll
        for (int dy = 0; dy < 4; ++dy) {
            int py = cy * 4 + dy + 1;
            #pragma unroll
            for (int dx = 0; dx < 4; ++dx) {
                int px = cx * 4 + dx + 1;
                double a00 = (double)esm[py - 1][px - 1];
                double a01 = (double)esm[py - 1][px];
                double a02 = (double)esm[py - 1][px + 1];
                double a10 = (double)esm[py][px - 1];
                double a12 = (double)esm[py][px + 1];
                double a20 = (double)esm[py + 1][px - 1];
                double a21 = (double)esm[py + 1][px];
                double a22 = (double)esm[py + 1][px + 1];
                double sx = (a02 + 2.0 * a12 + a22) - (a00 + 2.0 * a10 + a20);
                double sy = (a20 + 2.0 * a21 + a22) - (a00 + 2.0 * a01 + a02);
                acc += sqrt(sx * sx + sy * sy);
            }
        }
        double cell = acc * (1.0 / 16.0);
        int gy = (ty0 >> 2) + cy;
        int gx = (tx0 >> 2) + cx;
        edges[((size_t)b << 14) + gy * 128 + gx] = cell;
        double sc = cell;
        #pragma unroll
        for (int off = 32; off > 0; off >>= 1) sc += __shfl_xor(sc, off);
        if (lane == 0) dred[wid] = sc;
        __syncthreads();
        if (t == 0) tsum[b * 64 + tile] = dred[0] + dred[1] + dred[2] + dred[3];
    }
}

// ---------------- Kernel 2: per-batch mean, mask, prefix scan --------------
// one block per batch, 1024 threads, 16 cells/thread (R5-proven structure)
__global__ __launch_bounds__(1024) void k_scan(const double* __restrict__ edges,
                                               const double* __restrict__ tsum,
                                               int* __restrict__ pos,
                                               int* __restrict__ Karr,
                                               float* __restrict__ mask_out) {
    int b = blockIdx.x;
    int t = threadIdx.x;
    int lane = t & 63, wid = t >> 6;
    __shared__ int wcnt[16];
    // deterministic fixed-order fp64 mean (bit-identical across rounds)
    const double* ts = tsum + b * 64;
    double total = 0.0;
    #pragma unroll
    for (int j = 0; j < 64; ++j) total += ts[j];
    double mean = total * (1.0 / 16384.0);

    const double* e = edges + ((size_t)b << 14);
    double v[16];
    #pragma unroll
    for (int j = 0; j < 8; ++j) {
        double2 dv = *(const double2*)&e[t * 16 + j * 2];
        v[2 * j] = dv.x; v[2 * j + 1] = dv.y;
    }
    int m[16], cnt = 0;
    #pragma unroll
    for (int j = 0; j < 16; ++j) { m[j] = (v[j] > mean) ? 1 : 0; cnt += m[j]; }
    int incl = cnt;
    #pragma unroll
    for (int off = 1; off < 64; off <<= 1) {
        int up = __shfl_up(incl, off);
        if (lane >= off) incl += up;
    }
    if (lane == 63) wcnt[wid] = incl;
    __syncthreads();
    int woff = 0, Ktot = 0;
    #pragma unroll
    for (int w = 0; w < 16; ++w) { int c = wcnt[w]; Ktot += c; if (w < wid) woff += c; }
    int run = woff + incl - cnt;
    float mf[16]; int pv[16];
    #pragma unroll
    for (int j = 0; j < 16; ++j) {
        pv[j] = m[j] ? run : -1;
        run += m[j];
        mf[j] = m[j] ? 1.0f : 0.0f;
    }
    float* mb = mask_out + ((size_t)b << 14) + t * 16;
    int* pb = pos + ((size_t)b << 14) + t * 16;
    #pragma unroll
    for (int q = 0; q < 4; ++q) {
        *(float4*)&mb[q * 4] = make_float4(mf[4 * q], mf[4 * q + 1], mf[4 * q + 2], mf[4 * q + 3]);
        *(int4*)&pb[q * 4] = make_int4(pv[4 * q], pv[4 * q + 1], pv[4 * q + 2], pv[4 * q + 3]);
    }
    if (t == 0) Karr[b] = Ktot;
}

// ---------------- Kernel 3: fine embed — NO LDS, wave-uniform scalar loads -
// grid (512, 8), 256 threads. Wave-pair = 16 patches x 128 dims; patch index
// wave-uniform -> pixels and pos[] via SGPR loads; branches wave-uniform.
__global__ __launch_bounds__(256) void k_fine(const float* __restrict__ x,
                                              const float* __restrict__ wfp,
                                              const float* __restrict__ bfp,
                                              const float* __restrict__ temb,
                                              const int* __restrict__ pos,
                                              const int* __restrict__ Karr,
                                              float* __restrict__ out) {
    int b = blockIdx.y;
    int t = threadIdx.x;
    int lane = t & 63;
    int wv = __builtin_amdgcn_readfirstlane(t >> 6);  // wave id 0..3
    int h = wv & 1;                                   // dim half
    int p0 = blockIdx.x * 32 + (wv >> 1) * 16;        // 16 patches, one patch-row
    int d = h * 64 + lane;
    float wcol[16];
    #pragma unroll
    for (int k = 0; k < 16; ++k) wcol[k] = wfp[k * ED + d];
    float fill = temb[ED + d];
    float fbase = bfp[d] + fill;
    int K = Karr[b];
    const int* posb = pos + ((size_t)b << 14);
    int hf = p0 >> 7;                  // fine patch-row
    int wf0 = p0 & 127;                // patch-col offset (multiple of 16)
    const float* img = x + ((size_t)b * IMH + hf * 4) * IMW + wf0 * 4;
    float* tok = out + ((size_t)b * NTOK + NC) * ED;
    #pragma unroll
    for (int p = 0; p < 16; ++p) {
        int i = p0 + p;
        int ps = posb[i];                  // wave-uniform -> scalar load
        const float* pimg = img + p * 4;   // wave-uniform -> scalar loads
        float acc = fbase;
        #pragma unroll
        for (int r = 0; r < 4; ++r) {
            const float* rp = pimg + r * IMW;
            acc += rp[0] * wcol[4 * r + 0] + rp[1] * wcol[4 * r + 1]
                 + rp[2] * wcol[4 * r + 2] + rp[3] * wcol[4 * r + 3];
        }
        if (ps >= 0) {
            tok[(size_t)ps * ED + d] = acc;
        }
        if (i >= K) {
            tok[(size_t)i * ED + d] = fill;
        }
    }
}

extern "C" void kernel_launch(void* const* d_in, const int* in_sizes, int n_in,
                              void* d_out, int out_size, void* d_ws, size_t ws_size,
                              hipStream_t stream) {
    const float* x    = (const float*)d_in[0];
    const float* wc   = (const float*)d_in[1];
    const float* bc   = (const float*)d_in[2];
    const float* wfp  = (const float*)d_in[3];
    const float* bfp  = (const float*)d_in[4];
    const float* temb = (const float*)d_in[5];
    float* out = (float*)d_out;

    char* wsb = (char*)d_ws;
    double* edges = (double*)wsb;                                   // 1 MiB
    double* tsum  = (double*)(wsb + (size_t)BATCH * NF * 8);        // 4 KiB
    int* pos  = (int*)(wsb + (size_t)BATCH * NF * 8 + 4096);        // 512 KiB
    int* Karr = (int*)(wsb + (size_t)BATCH * NF * 8 + 4096 + (size_t)BATCH * NF * 4);
    float* mask_out = out + (size_t)BATCH * NTOK * ED;

    k1_edge_coarse<<<dim3(1536), 256, 0, stream>>>(x, wc, bc, temb, out, edges, tsum);
    k_scan<<<dim3(BATCH), 1024, 0, stream>>>(edges, tsum, pos, Karr, mask_out);
    k_fine<<<dim3(512, BATCH), 256, 0, stream>>>(x, wfp, bfp, temb, pos, Karr, out);
}